// Round 2
// 1811.762 us; speedup vs baseline: 1.0359x; 1.0359x over previous
//
#include <hip/hip_runtime.h>
#include <hip/hip_fp16.h>

#define BB 64
#define SS 1024
#define HD 256
#define GG 768   // 3*HD

typedef _Float16 h2_t __attribute__((ext_vector_type(2)));
typedef _Float16 h8_t __attribute__((ext_vector_type(8)));

#define FDOT2(a, b, c) __builtin_amdgcn_fdot2((a), (b), (c), false)

__device__ __forceinline__ float sigm(float x) {
    return 1.0f / (1.0f + __expf(-x));
}
__device__ __forceinline__ float tanh_fast(float x) {
    float e = __expf(2.0f * fabsf(x));
    float t = 1.0f - 2.0f / (e + 1.0f);
    return copysignf(t, x);
}

// DPP quad_perm butterfly add: reduce the 4 K-slice partials living in a lane quad.
// Pure VALU pipe -> no LDS traffic for the reduction.
__device__ __forceinline__ float quad_reduce(float x) {
    int t = __builtin_amdgcn_update_dpp(0, __float_as_int(x), 0xB1, 0xF, 0xF, true); // quad_perm xor 1
    x += __int_as_float(t);
    t = __builtin_amdgcn_update_dpp(0, __float_as_int(x), 0x4E, 0xF, 0xF, true);     // quad_perm xor 2
    x += __int_as_float(t);
    return x;
}

// Lane (wv, row=l>>2, sl=l&3) holds the K-slice [sl*64, sl*64+64) of 4 weight rows
// out_q = wv*64 + row + 16*q  (q = 0..3). 128 packed f16 pairs -> same VGPR budget as before.
__device__ __forceinline__ void load_wslices(const float* W, int wv, int row, int sl, h2_t w[4][32]) {
#pragma unroll
    for (int q = 0; q < 4; q++) {
        const float2* wr = (const float2*)(W + (size_t)(wv * 64 + row + 16 * q) * 256 + sl * 64);
#pragma unroll
        for (int k = 0; k < 32; k++) {
            float2 f = wr[k];
            h2_t p; p.x = (_Float16)f.x; p.y = (_Float16)f.y;
            w[q][k] = p;
        }
    }
}

// Bank-skewed LDS layout for a 256-f16 vector:
// element k lives at byte  (k>>6)*128 + ((((k>>3)&7) + 2*(k>>6)) & 7)*16 + (k&7)*2
// -> at each read step the 4 slices hit 4 disjoint bank quads (conflict-free),
//    while the weight index stays compile-time (no scratch spill).
__device__ __forceinline__ int swz256(int k) {
    int ksl = k >> 6;
    return ksl * 128 + ((((k >> 3) & 7) + 2 * ksl) & 7) * 16 + (k & 7) * 2;
}

// Partial dot over this lane's K-slice for its 4 output rows. 8 ds_read_b128 (vs 32 before).
__device__ __forceinline__ void dot_slices(const char* tbase, int sl, const h2_t w[4][32], float acc[4]) {
    const char* base = tbase + sl * 128;
#pragma unroll
    for (int j = 0; j < 8; j++) {
        h8_t v = *(const h8_t*)(base + ((((j + 2 * sl) & 7)) << 4));
        h2_t p0, p1, p2, p3;
        p0.x = v[0]; p0.y = v[1];
        p1.x = v[2]; p1.y = v[3];
        p2.x = v[4]; p2.y = v[5];
        p3.x = v[6]; p3.y = v[7];
#pragma unroll
        for (int q = 0; q < 4; q++) {
            acc[q] = FDOT2(w[q][4 * j + 0], p0, acc[q]);
            acc[q] = FDOT2(w[q][4 * j + 1], p1, acc[q]);
            acc[q] = FDOT2(w[q][4 * j + 2], p2, acc[q]);
            acc[q] = FDOT2(w[q][4 * j + 3], p3, acc[q]);
        }
    }
}

// producer/consumer flags: per-(role,batch) monotone chunk counters, 64B-padded
__device__ __forceinline__ void wait_ge(unsigned* f, unsigned v) {
    if (threadIdx.x == 0) {
        while (__hip_atomic_load(f, __ATOMIC_RELAXED, __HIP_MEMORY_SCOPE_AGENT) < v)
            __builtin_amdgcn_s_sleep(2);
        (void)__hip_atomic_load(f, __ATOMIC_ACQUIRE, __HIP_MEMORY_SCOPE_AGENT);
    }
    __syncthreads();
}
__device__ __forceinline__ void publish(unsigned* f, unsigned v) {
    __syncthreads();   // drains all waves' vmcnt (compiler emits waitcnt before barrier)
    if (threadIdx.x == 0)
        __hip_atomic_store(f, v, __ATOMIC_RELEASE, __HIP_MEMORY_SCOPE_AGENT);
}

// ---------------------------------------------------------------------------
// Persistent 4-stage pipeline: 256 blocks = 4 roles x 64 batches.
// role 0: P0  inputs -> xg0 ring          role 2: R0  xg0 -> h1 (cat)
// role 1: P1  h1(cat) -> xg1 ring         role 3: R1  xg1 -> h2 (out + cat)
// K-sliced dots: each lane reads only its 128B h-slice (8 ds_read_b128/step,
// 4x less LDS than full-broadcast dot256) + DPP quad reduction.
// ---------------------------------------------------------------------------
__global__ __launch_bounds__(GG, 3) void gru_pipe(
    const float* __restrict__ X,
    const float* __restrict__ Wih0, const float* __restrict__ bih0,
    const float* __restrict__ Whh0, const float* __restrict__ bhh0,
    const float* __restrict__ Wih1, const float* __restrict__ bih1,
    const float* __restrict__ Whh1, const float* __restrict__ bhh1,
    float* __restrict__ h2out, float* __restrict__ cat,
    float* __restrict__ ring0, float* __restrict__ ring1,
    unsigned* __restrict__ prog, int CT, int NS, int NC)
{
    __shared__ h8_t xs[2048];                 // 32 KB staging / h-state (rec uses first 512B, skewed)
    __shared__ float hf[HD], rs[HD], zs[HD];

    const int role = blockIdx.x >> 6;
    const int b    = blockIdx.x & 63;
    const int g    = threadIdx.x;
    const int wv   = g >> 6;
    const int l    = g & 63;
    const int row  = l >> 2;
    const int sl   = l & 3;
    const int out  = wv * 64 + row + 16 * sl;   // this lane's output index (bijective per wave)

    unsigned* f_p0 = prog + (0 * 64 + b) * 16;
    unsigned* f_p1 = prog + (1 * 64 + b) * 16;
    unsigned* f_r0 = prog + (2 * 64 + b) * 16;
    unsigned* f_r1 = prog + (3 * 64 + b) * 16;

    h2_t w[4][32];

    if (role == 0 || role == 1) {
        // ------- projection producer -------
        const float* Wp   = (role == 0) ? Wih0 : Wih1;
        const float* bp   = (role == 0) ? bih0 : bih1;
        const float* Xs   = (role == 0) ? X : cat;
        const int xstride = (role == 0) ? 256 : 512;
        float* ringo      = (role == 0) ? ring0 : ring1;
        unsigned* f_up    = (role == 0) ? nullptr : f_r0;   // P1 waits for h1 chunk
        unsigned* f_cons  = (role == 0) ? f_r0 : f_r1;      // ring reuse guard
        unsigned* f_out   = (role == 0) ? f_p0 : f_p1;

        load_wslices(Wp, wv, row, sl, w);
        const float bv = bp[out];
        char* xb = (char*)xs;

        for (int c = 0; c < NC; c++) {
            if (f_up) wait_ge(f_up, c + 1);
            if (c >= NS) wait_ge(f_cons, c - NS + 1);
            const int t0 = c * CT;
            for (int idx = g; idx < CT * 256; idx += GG) {
                int tt = idx >> 8, k = idx & 255;
                *(_Float16*)(xb + tt * 512 + swz256(k)) =
                    (_Float16)Xs[((size_t)b * SS + t0 + tt) * xstride + k];
            }
            __syncthreads();
            float* ro = ringo + ((size_t)b * NS + (c % NS)) * ((size_t)CT * GG) + out;
            for (int tt = 0; tt < CT; tt++) {
                float acc[4] = {0.f, 0.f, 0.f, 0.f};
                dot_slices(xb + tt * 512, sl, w, acc);
                float g0 = quad_reduce(acc[0]);
                float g1 = quad_reduce(acc[1]);
                float g2 = quad_reduce(acc[2]);
                float g3 = quad_reduce(acc[3]);
                float mine = (sl == 0) ? g0 : (sl == 1) ? g1 : (sl == 2) ? g2 : g3;
                ro[(size_t)tt * GG] = mine + bv;
            }
            publish(f_out, c + 1);   // its syncthreads also guards LDS reuse
        }
    } else {
        // ------- recurrence -------
        const float* Wp    = (role == 2) ? Whh0 : Whh1;
        const float* bp    = (role == 2) ? bhh0 : bhh1;
        const float* ringi = (role == 2) ? ring0 : ring1;
        unsigned* f_in  = (role == 2) ? f_p0 : f_p1;
        unsigned* f_out = (role == 2) ? f_r0 : f_r1;
        float* outA   = (role == 2) ? cat : h2out;
        int   strideA = (role == 2) ? 512 : 256;
        float* outB   = (role == 2) ? nullptr : (cat + 256);   // stride 512

        load_wslices(Wp, wv, row, sl, w);
        const float bv = bp[out];
        const int cls = wv >> 2;    // 0=r, 1=z, 2=n  (wave-uniform)
        const int i   = out & 255;
        char* xb = (char*)xs;
        // precomputed skewed write slot for this lane's h element (cls==2 lanes)
        _Float16* hws = (_Float16*)(xb + swz256(i));

        if (g < HD) { hf[g] = 0.0f; ((unsigned short*)xs)[g] = 0; }  // zeros are swizzle-invariant
        __syncthreads();

        for (int c = 0; c < NC; c++) {
            wait_ge(f_in, c + 1);
            const float* xgp = ringi + ((size_t)b * NS + (c % NS)) * ((size_t)CT * GG) + out;
            float xv = xgp[0];
            for (int tt = 0; tt < CT; tt++) {
                float xv_next = (tt + 1 < CT) ? xgp[(size_t)(tt + 1) * GG] : 0.0f;
                float acc[4] = {0.f, 0.f, 0.f, 0.f};
                dot_slices(xb, sl, w, acc);          // hidden-side gate pre-act (partial)
                float g0 = quad_reduce(acc[0]);
                float g1 = quad_reduce(acc[1]);
                float g2 = quad_reduce(acc[2]);
                float g3 = quad_reduce(acc[3]);
                float hd = ((sl == 0) ? g0 : (sl == 1) ? g1 : (sl == 2) ? g2 : g3) + bv;
                if (cls == 0)      rs[i] = sigm(xv + hd);
                else if (cls == 1) zs[i] = sigm(xv + hd);
                __syncthreads();
                if (cls == 2) {
                    float r = rs[i], z = zs[i], hp = hf[i];
                    float n = tanh_fast(xv + r * hd);
                    float hnew = (1.0f - z) * n + z * hp;
                    hf[i] = hnew;
                    *hws = (_Float16)hnew;
                    size_t t = (size_t)(c * CT + tt);
                    outA[((size_t)b * SS + t) * strideA + i] = hnew;
                    if (outB) outB[((size_t)b * SS + t) * 512 + i] = hnew;
                }
                __syncthreads();
                xv = xv_next;
            }
            publish(f_out, c + 1);
        }
    }
}

// ---------------------------------------------------------------------------
extern "C" void kernel_launch(void* const* d_in, const int* in_sizes, int n_in,
                              void* d_out, int out_size, void* d_ws, size_t ws_size,
                              hipStream_t stream)
{
    const float* inputs = (const float*)d_in[0];
    const float* W_ih0  = (const float*)d_in[1];
    const float* W_hh0  = (const float*)d_in[2];
    const float* b_ih0  = (const float*)d_in[3];
    const float* b_hh0  = (const float*)d_in[4];
    const float* W_ih1  = (const float*)d_in[5];
    const float* W_hh1  = (const float*)d_in[6];
    const float* b_ih1  = (const float*)d_in[7];
    const float* b_hh1  = (const float*)d_in[8];

    float* h2out = (float*)d_out;                    // [B,S,256]
    float* cat   = h2out + (size_t)BB * SS * HD;     // [B,S,512] = [h1 | h2]

    unsigned char* ws = (unsigned char*)d_ws;
    unsigned* prog = (unsigned*)ws;
    const size_t FLAG_BYTES = 4 * 64 * 16 * sizeof(unsigned);   // 64B-padded counters
    size_t avail = ws_size > FLAG_BYTES ? ws_size - FLAG_BYTES : 0;

    // pick chunk length CT and ring slots NS to fit workspace
    int CT = 64, NS = 0;
    for (;;) {
        size_t slot = (size_t)BB * CT * GG * sizeof(float);   // one slot, one ring
        size_t m = slot ? avail / (2 * slot) : 0;
        int nc = SS / CT;
        NS = (int)(m < (size_t)nc ? m : (size_t)nc);
        if (NS >= 2 || CT == 8) break;
        CT >>= 1;
    }
    if (NS < 1) NS = 1;
    int NC = SS / CT;

    float* ring0 = (float*)(ws + FLAG_BYTES);
    float* ring1 = ring0 + (size_t)BB * NS * CT * GG;

    hipMemsetAsync(prog, 0, FLAG_BYTES, stream);
    gru_pipe<<<256, GG, 0, stream>>>(inputs,
                                     W_ih0, b_ih0, W_hh0, b_hh0,
                                     W_ih1, b_ih1, W_hh1, b_hh1,
                                     h2out, cat, ring0, ring1, prog, CT, NS, NC);
}